// Round 15
// baseline (202.900 us; speedup 1.0000x reference)
//
#include <hip/hip_runtime.h>

#define H      128
#define OBSROW 141
#define GPB    32     // graphs per block (2 x 16-graph MFMA column tiles)
#define NT     1024   // 16 waves = 8 channel-groups x 2 graph-halves

typedef __bf16 bf16x8 __attribute__((ext_vector_type(8)));
typedef float  f32x4  __attribute__((ext_vector_type(4)));

__device__ __forceinline__ float eluf(float v) {
    return v > 0.0f ? v : (__expf(v) - 1.0f);
}
__device__ __forceinline__ f32x4 mf(bf16x8 a, bf16x8 b, f32x4 c) {
    return __builtin_amdgcn_mfma_f32_16x16x32_bf16(a, b, c, 0, 0, 0);
}
// elu 4 floats -> 4 bf16, one aligned b64 store
__device__ __forceinline__ void store_pk4(unsigned short* dst, f32x4 a) {
    union { unsigned short u[4]; unsigned long long v; } pk;
    #pragma unroll
    for (int r = 0; r < 4; r++) {
        __bf16 b = (__bf16)eluf(a[r]);
        pk.u[r] = *(unsigned short*)&b;
    }
    *(unsigned long long*)dst = pk.v;
}

// ws (bf16 elems): [0)Wrel 3*16384 | [49152)Wroot 3*16384 | [98304)We_b pad[128][64] | [106496)We_j pad[128][32]
#define WS_ROOT 49152
#define WS_EB   98304
#define WS_EJ   106496
#define WS_TOT  110592

__global__ void convert_weights(const float* __restrict__ Wr, const float* __restrict__ Wo,
                                const float* __restrict__ Web, const float* __restrict__ Wej,
                                __bf16* __restrict__ ws) {
    const int i = blockIdx.x * 256 + threadIdx.x;
    if (i < WS_ROOT) {
        ws[i] = (__bf16)Wr[i];
    } else if (i < WS_EB) {
        ws[i] = (__bf16)Wo[i - WS_ROOT];
    } else if (i < WS_EJ) {
        const int j = i - WS_EB, o = j >> 6, f = j & 63;
        ws[i] = (__bf16)(f < 33 ? Web[o*33 + f] : 0.0f);
    } else if (i < WS_TOT) {
        const int j = i - WS_EJ, o = j >> 5, f = j & 31;
        ws[i] = (__bf16)(f < 9 ? Wej[o*9 + f] : 0.0f);
    }
}

// X layout: [node 13][hc 16][graph 32][hi 8] bf16; channel = hc*8+hi
// ushort addr = n*4096 + hc*256 + g*8 + hi   (8192 B per node, 104 KB total)
// Fs: gathered features [jj 12][fc 4][g 32][hi 8] + base [fc 8][g 32][hi 8] = 28672 B.
// Dec (decoder partials, 12 KB) aliases Fs -- Fs is dead after the encoder.

__launch_bounds__(NT, 4)   // 4 waves/EU -> 128-reg cap; body ~100 unified -> no spill.
                           // 1 block/CU (LDS 135168) = 16 waves/CU, same as champion.
__global__ void gnn_fused(const float* __restrict__ obs,
                          const float* __restrict__ be_b, const float* __restrict__ be_j,
                          const float* __restrict__ b_rel,
                          const float* __restrict__ W_dec, const float* __restrict__ b_dec,
                          const __bf16* __restrict__ wsb,
                          float* __restrict__ out, int B)
{
    __shared__ __align__(16) unsigned short Xs[13*4096];   // 106496 B node features
    __shared__ __align__(16) unsigned short Fs[14336];     //  28672 B gathered / Dec alias

    const int tid  = threadIdx.x;
    const int wave = tid >> 6;     // 0..15
    const int chg  = wave & 7;     // channel group -> channels [chg*16, chg*16+16)
    const int gset = wave >> 3;    // graph half -> graphs [gset*16, gset*16+16)
    const int lane = tid & 63;
    const int q    = lane >> 4;    // k-quarter (inputs) / channel-quad (output)
    const int c    = lane & 15;    // graph-in-half (B-side) == weight row offset (A-side)
    const int g    = gset*16 + c;  // graph-in-block
    const int g0   = blockIdx.x * GPB;

    static constexpr int ODEG[13]    = {4,2,2,1,2,2,1,2,2,1,2,2,1};
    static constexpr int ODST[13][4] = {
        {1,4,7,10},{0,2,0,0},{1,3,0,0},{2,0,0,0},{0,5,0,0},{4,6,0,0},{5,0,0,0},
        {0,8,0,0},{7,9,0,0},{8,0,0,0},{0,11,0,0},{10,12,0,0},{11,0,0,0}};

    // swapped-operand output: lane (q,c) holds graph g, channels o = chg*16 + q*4 + r
    const int hcd  = chg*2 + (q>>1);           // destination hc
    const int wofs = g*8 + (q&1)*4;            // graph*8 + hi base (ushort units)

    // ---------- fused gather: global obs -> Fs (bf16) ----------
    {
        // joints at Fs[jj*1024 + fc*256 + g*8 + hi] (f = fc*8+hi, f<9 valid)
        for (int s = tid; s < 12288; s += NT) {
            const int jj = s >> 10, rem = s & 1023;
            const int fc = rem >> 8, gg = (rem >> 3) & 31, hi = rem & 7;
            const int f = fc*8 + hi;
            float v = 0.0f;
            if (f < 9 && (g0 + gg) < B)
                v = obs[(g0+gg)*OBSROW + (f/3)*47 + 9 + (f%3)*12 + jj];
            *(__bf16*)&Fs[s] = (__bf16)v;
        }
        // base at Fs[12288 + fc*256 + g*8 + hi] (f = fc*8+hi, f<33 valid, K padded to 64)
        for (int s = tid; s < 2048; s += NT) {
            const int fc = s >> 8, rem = s & 255, gg = rem >> 3, hi = rem & 7;
            const int f = fc*8 + hi;
            float v = 0.0f;
            if (f < 33 && (g0 + gg) < B) {
                const int tt = f / 11, i2 = f % 11;   // BASE_IDX[i] = i<9 ? i : 36+i
                v = obs[(g0+gg)*OBSROW + tt*47 + (i2 < 9 ? i2 : 36 + i2)];
            }
            *(__bf16*)&Fs[12288 + s] = (__bf16)v;
        }
    }
    __syncthreads();

    // ---------------- encoders (A = weights, B = features) ----------------
    {
        const int orow = chg*16 + c;
        // node 0 (base), K=64 padded -> 2 MFMAs
        {
            const bf16x8 u0 = *(const bf16x8*)(wsb + WS_EB + orow*64 + q*8);
            const bf16x8 u1 = *(const bf16x8*)(wsb + WS_EB + orow*64 + 32 + q*8);
            const bf16x8 a0 = *(const bf16x8*)&Fs[12288 + q*256 + g*8];
            const bf16x8 a1 = *(const bf16x8*)&Fs[12288 + 1024 + q*256 + g*8];
            const float4 b4 = *(const float4*)&be_b[chg*16 + q*4];
            f32x4 acc = {b4.x, b4.y, b4.z, b4.w};
            acc = mf(u0, a0, acc);
            acc = mf(u1, a1, acc);
            store_pk4(&Xs[hcd*256 + wofs], acc);
        }
        // joints 0..11, K=32 -> 1 MFMA each
        {
            const bf16x8 uj = *(const bf16x8*)(wsb + WS_EJ + orow*32 + q*8);
            const float4 b4 = *(const float4*)&be_j[chg*16 + q*4];
            const f32x4 bias = {b4.x, b4.y, b4.z, b4.w};
            #pragma unroll
            for (int jj = 0; jj < 12; jj++) {
                const bf16x8 a = *(const bf16x8*)&Fs[jj*1024 + q*256 + g*8];
                f32x4 acc = bias;
                acc = mf(uj, a, acc);
                store_pk4(&Xs[(1+jj)*4096 + hcd*256 + wofs], acc);
            }
        }
    }
    __syncthreads();

    // ---------------- GraphConv layers 0,1 (champion body; graph-half offset) ----------
    // B-frag (X) for (n,ks): Xs + n*4096 + ks*1024 + q*256 + g*8 (contiguous 256B/quad)
    // A-frag (W) for ks:     w + (chg*16+c)*128 + ks*32 + q*8
    const unsigned short* xr = Xs + q*256 + g*8;
    #pragma unroll 1
    for (int l = 0; l < 2; l++) {
        const __bf16* wr = wsb + l*16384 + (chg*16 + c)*128 + q*8;
        const __bf16* wo = wsb + WS_ROOT + l*16384 + (chg*16 + c)*128 + q*8;
        const float4 b4 = *(const float4*)&b_rel[l*H + chg*16 + q*4];
        const f32x4 bias = {b4.x, b4.y, b4.z, b4.w};

        f32x4 acc[13];
        #pragma unroll
        for (int n = 0; n < 13; n++) acc[n] = bias;

        #pragma unroll 1
        for (int h = 0; h < 2; h++) {
            const bf16x8 br0 = *(const bf16x8*)(wr + h*64);
            const bf16x8 br1 = *(const bf16x8*)(wr + h*64 + 32);
            const bf16x8 bo0 = *(const bf16x8*)(wo + h*64);
            const bf16x8 bo1 = *(const bf16x8*)(wo + h*64 + 32);
            const unsigned short* xh = xr + h*2048;
            #pragma unroll
            for (int n = 0; n < 13; n++) {
                const bf16x8 xa0 = *(const bf16x8*)(xh + n*4096);
                const bf16x8 xa1 = *(const bf16x8*)(xh + n*4096 + 1024);
                acc[n] = mf(bo0, xa0, acc[n]);
                acc[n] = mf(bo1, xa1, acc[n]);
                #pragma unroll
                for (int e = 0; e < 4; e++) {
                    if (e < ODEG[n]) {
                        const int d = ODST[n][e];
                        acc[d] = mf(br0, xa0, acc[d]);
                        acc[d] = mf(br1, xa1, acc[d]);
                    }
                }
            }
        }
        __syncthreads();   // A: all X reads done
        #pragma unroll
        for (int n = 0; n < 13; n++)
            store_pk4(&Xs[n*4096 + hcd*256 + wofs], acc[n]);
        __syncthreads();   // B: new X visible
    }

    // ---------------- layer 2 + fused decoder (no X2 stores) ----------------
    {
        const __bf16* wr = wsb + 2*16384 + (chg*16 + c)*128 + q*8;
        const __bf16* wo = wsb + WS_ROOT + 2*16384 + (chg*16 + c)*128 + q*8;
        const float4 b4 = *(const float4*)&b_rel[2*H + chg*16 + q*4];
        const f32x4 bias = {b4.x, b4.y, b4.z, b4.w};

        f32x4 acc[13];
        #pragma unroll
        for (int n = 0; n < 13; n++) acc[n] = bias;

        #pragma unroll 1
        for (int h = 0; h < 2; h++) {
            const bf16x8 br0 = *(const bf16x8*)(wr + h*64);
            const bf16x8 br1 = *(const bf16x8*)(wr + h*64 + 32);
            const bf16x8 bo0 = *(const bf16x8*)(wo + h*64);
            const bf16x8 bo1 = *(const bf16x8*)(wo + h*64 + 32);
            const unsigned short* xh = xr + h*2048;
            #pragma unroll
            for (int n = 0; n < 13; n++) {
                const bf16x8 xa0 = *(const bf16x8*)(xh + n*4096);
                const bf16x8 xa1 = *(const bf16x8*)(xh + n*4096 + 1024);
                if (n != 0) {                          // node-0 output dead in last layer
                    acc[n] = mf(bo0, xa0, acc[n]);
                    acc[n] = mf(bo1, xa1, acc[n]);
                }
                #pragma unroll
                for (int e = 0; e < 4; e++) {
                    if (e < ODEG[n]) {
                        const int d = ODST[n][e];
                        if (d == 0) continue;          // dead output
                        acc[d] = mf(br0, xa0, acc[d]);
                        acc[d] = mf(br1, xa1, acc[d]);
                    }
                }
            }
        }
        // No barrier: decoder uses only this wave's registers; Dec aliases Fs, which
        // has been dead since the encoder barrier.

        // decoder on f32 accumulators: p[j] = sum_ch elu(x2[j+1][ch]) * W_dec[ch]
        float wd[4];
        {
            const float4 w4 = *(const float4*)&W_dec[chg*16 + q*4];
            wd[0] = w4.x; wd[1] = w4.y; wd[2] = w4.z; wd[3] = w4.w;
        }
        float* Dec = (float*)Fs;   // [8 chgroups][12 joints][32 graphs] f32 = 12 KB
        #pragma unroll
        for (int j = 0; j < 12; j++) {
            float pp = 0.0f;
            #pragma unroll
            for (int r = 0; r < 4; r++)
                pp += eluf(acc[j+1][r]) * wd[r];
            pp += __shfl_xor(pp, 16);   // sum over q (channel quads)
            pp += __shfl_xor(pp, 32);
            if (q == 0)
                Dec[chg*384 + j*32 + g] = pp;
        }
        __syncthreads();   // partials visible
        if (tid < 384) {   // t = c2*12 + j2 -> coalesced out stores
            const int c2 = tid / 12, j2 = tid - c2*12;
            float ssum = 0.0f;
            #pragma unroll
            for (int w = 0; w < 8; w++)
                ssum += Dec[w*384 + j2*32 + c2];
            if ((g0 + c2) < B)
                out[(g0 + c2)*12 + j2] = ssum + b_dec[0];
        }
    }
}

extern "C" void kernel_launch(void* const* d_in, const int* in_sizes, int n_in,
                              void* d_out, int out_size, void* d_ws, size_t ws_size,
                              hipStream_t stream) {
    const float* obs   = (const float*)d_in[0];
    const float* We_b  = (const float*)d_in[1];
    const float* be_b  = (const float*)d_in[2];
    const float* We_j  = (const float*)d_in[3];
    const float* be_j  = (const float*)d_in[4];
    const float* W_rel = (const float*)d_in[5];
    const float* W_root= (const float*)d_in[6];
    const float* b_rel = (const float*)d_in[7];
    const float* W_dec = (const float*)d_in[8];
    const float* b_dec = (const float*)d_in[9];
    float* out = (float*)d_out;
    __bf16* wsb = (__bf16*)d_ws;

    const int B = in_sizes[0] / OBSROW;
    convert_weights<<<(WS_TOT + 255) / 256, 256, 0, stream>>>(W_rel, W_root, We_b, We_j, wsb);
    const int blocks = (B + GPB - 1) / GPB;
    gnn_fused<<<blocks, NT, 0, stream>>>(obs, be_b, be_j, b_rel, W_dec, b_dec,
                                         wsb, out, B);
}

// Round 16
// 188.038 us; speedup vs baseline: 1.0790x; 1.0790x over previous
//
#include <hip/hip_runtime.h>

#define H      128
#define OBSROW 141
#define GPB    16     // graphs per block (MFMA N dimension)
#define NT     512    // 8 waves; each wave owns 16 output channels (one 16x16 o-subtile)

typedef __bf16 bf16x8 __attribute__((ext_vector_type(8)));
typedef float  f32x4  __attribute__((ext_vector_type(4)));

__device__ __forceinline__ float eluf(float v) {
    return v > 0.0f ? v : (__expf(v) - 1.0f);
}
__device__ __forceinline__ f32x4 mf(bf16x8 a, bf16x8 b, f32x4 c) {
    return __builtin_amdgcn_mfma_f32_16x16x32_bf16(a, b, c, 0, 0, 0);
}
// elu 4 floats -> 4 bf16, one aligned b64 store
__device__ __forceinline__ void store_pk4(unsigned short* dst, f32x4 a) {
    union { unsigned short u[4]; unsigned long long v; } pk;
    #pragma unroll
    for (int r = 0; r < 4; r++) {
        __bf16 b = (__bf16)eluf(a[r]);
        pk.u[r] = *(unsigned short*)&b;
    }
    *(unsigned long long*)dst = pk.v;
}

// ws (bf16 elems): [0)Wrel 3*16384 | [49152)Wroot 3*16384 | [98304)We_b pad[128][64] | [106496)We_j pad[128][32]
#define WS_ROOT 49152
#define WS_EB   98304
#define WS_EJ   106496
#define WS_TOT  110592

__global__ void convert_weights(const float* __restrict__ Wr, const float* __restrict__ Wo,
                                const float* __restrict__ Web, const float* __restrict__ Wej,
                                __bf16* __restrict__ ws) {
    const int i = blockIdx.x * 256 + threadIdx.x;
    if (i < WS_ROOT) {
        ws[i] = (__bf16)Wr[i];
    } else if (i < WS_EB) {
        ws[i] = (__bf16)Wo[i - WS_ROOT];
    } else if (i < WS_EJ) {
        const int j = i - WS_EB, o = j >> 6, f = j & 63;
        ws[i] = (__bf16)(f < 33 ? Web[o*33 + f] : 0.0f);
    } else if (i < WS_TOT) {
        const int j = i - WS_EJ, o = j >> 5, f = j & 31;
        ws[i] = (__bf16)(f < 9 ? Wej[o*9 + f] : 0.0f);
    }
}

// X layout: [node 13][hc 16][graph 16][hi 8] bf16; channel = hc*8+hi
// Fs: separate gathered-feature buffer; reused as f32 decoder partials at the end.

__launch_bounds__(NT, 4)   // 4 waves/EU -> 128-reg cap; champion body ~52 VGPR +
                           // 8 in-layer frags (16) + preloaded biases (12) ~ 80 -> no
                           // spill. 2 blocks/CU (LDS 67584*2 <= 163840) = 16 waves/CU.
__global__ void gnn_fused(const float* __restrict__ obs,
                          const float* __restrict__ be_b, const float* __restrict__ be_j,
                          const float* __restrict__ b_rel,
                          const float* __restrict__ W_dec, const float* __restrict__ b_dec,
                          const __bf16* __restrict__ wsb,
                          float* __restrict__ out, int B)
{
    __shared__ __align__(16) unsigned short Xs[13*2048];   // 53248 B node features
    __shared__ __align__(16) unsigned short Fs[7168];      // 14336 B gathered / partials

    const int tid  = threadIdx.x;
    const int wave = tid >> 6;     // 0..7 -> channels [wave*16, wave*16+16)
    const int lane = tid & 63;
    const int q    = lane >> 4;    // k-quarter (inputs) / channel-quad (output)
    const int c    = lane & 15;    // graph (B-side) == weight output-row offset (A-side)
    const int g0   = blockIdx.x * GPB;

    static constexpr int ODEG[13]    = {4,2,2,1,2,2,1,2,2,1,2,2,1};
    static constexpr int ODST[13][4] = {
        {1,4,7,10},{0,2,0,0},{1,3,0,0},{2,0,0,0},{0,5,0,0},{4,6,0,0},{5,0,0,0},
        {0,8,0,0},{7,9,0,0},{8,0,0,0},{0,11,0,0},{10,12,0,0},{11,0,0,0}};

    // swapped-operand output: lane (q,c) holds graph c, channels o = wave*16 + q*4 + r
    const int hcd  = wave*2 + (q>>1);          // destination hc
    const int wofs = c*8 + (q&1)*4;            // graph*8 + hi base (ushort units)

    // ---- preload per-layer biases + decoder weights ONCE (removes the global-load
    //      gate at each post-barrier layer head; 12 regs) ----
    f32x4 lbias[3];
    #pragma unroll
    for (int l = 0; l < 3; l++) {
        const float4 b4 = *(const float4*)&b_rel[l*H + wave*16 + q*4];
        lbias[l] = (f32x4){b4.x, b4.y, b4.z, b4.w};
    }
    float wd[4];
    {
        const float4 w4 = *(const float4*)&W_dec[wave*16 + q*4];
        wd[0] = w4.x; wd[1] = w4.y; wd[2] = w4.z; wd[3] = w4.w;
    }
    const float bdv = b_dec[0];

    // ---------- fused gather: global obs -> Fs (bf16) ----------
    {
        // joints at Fs[jj*512 + fc*128 + g*8 + hi] (f = fc*8+hi, f<9 valid)
        for (int s = tid; s < 6144; s += NT) {
            const int jj = s >> 9, rem = s & 511;
            const int fc = rem >> 7, g = (rem >> 3) & 15, hi = rem & 7;
            const int f = fc*8 + hi;
            float v = 0.0f;
            if (f < 9 && (g0 + g) < B)
                v = obs[(g0+g)*OBSROW + (f/3)*47 + 9 + (f%3)*12 + jj];
            *(__bf16*)&Fs[s] = (__bf16)v;
        }
        // base at Fs[6144 + fc*128 + g*8 + hi] (f = fc*8+hi, f<33 valid, K padded to 64)
        for (int s = tid; s < 1024; s += NT) {
            const int fc = s >> 7, rem = s & 127, g = rem >> 3, hi = rem & 7;
            const int f = fc*8 + hi;
            float v = 0.0f;
            if (f < 33 && (g0 + g) < B) {
                const int tt = f / 11, i2 = f % 11;   // BASE_IDX[i] = i<9 ? i : 36+i
                v = obs[(g0+g)*OBSROW + tt*47 + (i2 < 9 ? i2 : 36 + i2)];
            }
            *(__bf16*)&Fs[6144 + s] = (__bf16)v;
        }
    }
    __syncthreads();

    // ---------------- encoders (A = weights, B = features) ----------------
    {
        const int orow = wave*16 + c;
        // node 0 (base), K=64 padded -> 2 MFMAs
        {
            const bf16x8 u0 = *(const bf16x8*)(wsb + WS_EB + orow*64 + q*8);
            const bf16x8 u1 = *(const bf16x8*)(wsb + WS_EB + orow*64 + 32 + q*8);
            const bf16x8 a0 = *(const bf16x8*)&Fs[6144 + q*128 + c*8];
            const bf16x8 a1 = *(const bf16x8*)&Fs[6144 + 512 + q*128 + c*8];
            const float4 b4 = *(const float4*)&be_b[wave*16 + q*4];
            f32x4 acc = {b4.x, b4.y, b4.z, b4.w};
            acc = mf(u0, a0, acc);
            acc = mf(u1, a1, acc);
            store_pk4(&Xs[hcd*128 + wofs], acc);
        }
        // joints 0..11, K=32 -> 1 MFMA each
        {
            const bf16x8 uj = *(const bf16x8*)(wsb + WS_EJ + orow*32 + q*8);
            const float4 b4 = *(const float4*)&be_j[wave*16 + q*4];
            const f32x4 bias = {b4.x, b4.y, b4.z, b4.w};
            #pragma unroll
            for (int jj = 0; jj < 12; jj++) {
                const bf16x8 a = *(const bf16x8*)&Fs[jj*512 + q*128 + c*8];
                f32x4 acc = bias;
                acc = mf(uj, a, acc);
                store_pk4(&Xs[(1+jj)*2048 + hcd*128 + wofs], acc);
            }
        }
    }
    __syncthreads();

    // ---------------- GraphConv layers 0,1 (all 8 frags at head, h unrolled) ----------
    // B-frag (X) for (n,ks): Xs + n*2048 + ks*512 + q*128 + c*8 (wave-contiguous 1KB)
    // A-frag (W) for ks:     w + (wave*16+c)*128 + ks*32 + q*8
    // Frag lifetime stays WITHIN the layer (no cross-barrier liveness - R12's mistake).
    const unsigned short* xr = Xs + q*128 + c*8;
    #pragma unroll 1
    for (int l = 0; l < 2; l++) {
        const __bf16* wr = wsb + l*16384 + (wave*16 + c)*128 + q*8;
        const __bf16* wo = wsb + WS_ROOT + l*16384 + (wave*16 + c)*128 + q*8;
        bf16x8 br[4], bo[4];
        #pragma unroll
        for (int ks = 0; ks < 4; ks++) {
            br[ks] = *(const bf16x8*)(wr + ks*32);
            bo[ks] = *(const bf16x8*)(wo + ks*32);
        }
        f32x4 acc[13];
        #pragma unroll
        for (int n = 0; n < 13; n++) acc[n] = lbias[l];

        #pragma unroll
        for (int h = 0; h < 2; h++) {
            const unsigned short* xh = xr + h*1024;
            #pragma unroll
            for (int n = 0; n < 13; n++) {
                const bf16x8 xa0 = *(const bf16x8*)(xh + n*2048);
                const bf16x8 xa1 = *(const bf16x8*)(xh + n*2048 + 512);
                acc[n] = mf(bo[2*h  ], xa0, acc[n]);
                acc[n] = mf(bo[2*h+1], xa1, acc[n]);
                #pragma unroll
                for (int e = 0; e < 4; e++) {
                    if (e < ODEG[n]) {
                        const int d = ODST[n][e];
                        acc[d] = mf(br[2*h  ], xa0, acc[d]);
                        acc[d] = mf(br[2*h+1], xa1, acc[d]);
                    }
                }
            }
        }
        __syncthreads();   // A: all X reads done
        #pragma unroll
        for (int n = 0; n < 13; n++)
            store_pk4(&Xs[n*2048 + hcd*128 + wofs], acc[n]);
        __syncthreads();   // B: new X visible
    }

    // ---------------- layer 2 + fused decoder (no X2 stores, no trailing barrier) ----
    {
        const __bf16* wr = wsb + 2*16384 + (wave*16 + c)*128 + q*8;
        const __bf16* wo = wsb + WS_ROOT + 2*16384 + (wave*16 + c)*128 + q*8;
        bf16x8 br[4], bo[4];
        #pragma unroll
        for (int ks = 0; ks < 4; ks++) {
            br[ks] = *(const bf16x8*)(wr + ks*32);
            bo[ks] = *(const bf16x8*)(wo + ks*32);
        }
        f32x4 acc[13];
        #pragma unroll
        for (int n = 0; n < 13; n++) acc[n] = lbias[2];

        #pragma unroll
        for (int h = 0; h < 2; h++) {
            const unsigned short* xh = xr + h*1024;
            #pragma unroll
            for (int n = 0; n < 13; n++) {
                const bf16x8 xa0 = *(const bf16x8*)(xh + n*2048);
                const bf16x8 xa1 = *(const bf16x8*)(xh + n*2048 + 512);
                if (n != 0) {                          // node-0 output dead in last layer
                    acc[n] = mf(bo[2*h  ], xa0, acc[n]);
                    acc[n] = mf(bo[2*h+1], xa1, acc[n]);
                }
                #pragma unroll
                for (int e = 0; e < 4; e++) {
                    if (e < ODEG[n]) {
                        const int d = ODST[n][e];
                        if (d == 0) continue;          // dead output
                        acc[d] = mf(br[2*h  ], xa0, acc[d]);
                        acc[d] = mf(br[2*h+1], xa1, acc[d]);
                    }
                }
            }
        }
        // No barrier needed: decoder uses only this wave's registers + Fs (dead since
        // the encoder barrier).

        // decoder on f32 accumulators: p[j] = sum_ch elu(x2[j+1][ch]) * W_dec[ch]
        float* part = (float*)Fs;   // [8 waves][12 joints][16 graphs] f32 = 6 KB
        #pragma unroll
        for (int j = 0; j < 12; j++) {
            float pp = 0.0f;
            #pragma unroll
            for (int r = 0; r < 4; r++)
                pp += eluf(acc[j+1][r]) * wd[r];
            pp += __shfl_xor(pp, 16);   // sum over q (channel quads)
            pp += __shfl_xor(pp, 32);
            if (q == 0)
                part[wave*192 + j*16 + c] = pp;
        }
        __syncthreads();
        if (tid < 192) {   // t = c2*12 + j2 -> coalesced out stores
            const int c2 = tid / 12, j2 = tid - c2*12;
            float ssum = 0.0f;
            #pragma unroll
            for (int w = 0; w < 8; w++)
                ssum += part[w*192 + j2*16 + c2];
            if ((g0 + c2) < B)
                out[(g0 + c2)*12 + j2] = ssum + bdv;
        }
    }
}

extern "C" void kernel_launch(void* const* d_in, const int* in_sizes, int n_in,
                              void* d_out, int out_size, void* d_ws, size_t ws_size,
                              hipStream_t stream) {
    const float* obs   = (const float*)d_in[0];
    const float* We_b  = (const float*)d_in[1];
    const float* be_b  = (const float*)d_in[2];
    const float* We_j  = (const float*)d_in[3];
    const float* be_j  = (const float*)d_in[4];
    const float* W_rel = (const float*)d_in[5];
    const float* W_root= (const float*)d_in[6];
    const float* b_rel = (const float*)d_in[7];
    const float* W_dec = (const float*)d_in[8];
    const float* b_dec = (const float*)d_in[9];
    float* out = (float*)d_out;
    __bf16* wsb = (__bf16*)d_ws;

    const int B = in_sizes[0] / OBSROW;
    convert_weights<<<(WS_TOT + 255) / 256, 256, 0, stream>>>(W_rel, W_root, We_b, We_j, wsb);
    const int blocks = (B + GPB - 1) / GPB;
    gnn_fused<<<blocks, NT, 0, stream>>>(obs, be_b, be_j, b_rel, W_dec, b_dec,
                                         wsb, out, B);
}